// Round 4
// baseline (248.592 us; speedup 1.0000x reference)
//
#include <hip/hip_runtime.h>

// Pre-emphasis IIR: out[t] = y[t] + 0.85*out[t-1], shift SKIP=91, scale 32768,
// clip, astype(int16) (trunc toward zero); harness reads d_out as int32.
//
// R3 -> R4: occupancy fix (37->68%) gave zero speedup -> issue/latency-bound
// on instruction count + 3-barrier structure, not occupancy. This round:
// b128 LDS ops via +4/32 padding (16B alignment preserved), WARM=71 so the
// global stage stays 16B-aligned, direct int4 stores (no LDS bounce),
// 1 barrier. ~300 instrs/thread vs ~700.

#define BLOCK   256
#define CH      16
#define TILE    (BLOCK * CH)        // 4096
#define SKIP    91
#define WARM    71                  // tStart = tileBase + 20 (16B-aligned)
#define COEF    0.85f
#define RD      (WARM + CH + 1)     // 88 floats = 22 float4 per thread
#define LOADN   (TILE + 72)         // 4168 floats staged (mult of 4)
#define PAD4(p) ((p) + 4 * ((p) >> 5))   // 4-aligned p stays 16B-aligned
#define LDS_F   4696                // > PAD4(4167)=4687, rounded to mult of 4

__global__ __launch_bounds__(BLOCK) void preemph_kernel(
        const float* __restrict__ sig, int* __restrict__ out, int n) {
    __shared__ float lds[LDS_F];
    const int  tid      = threadIdx.x;
    const long tileBase = (long)blockIdx.x * TILE;
    const long tStart   = tileBase + (SKIP - WARM - 1) + 1; // tileBase + 20

    float4* const       l4w = reinterpret_cast<float4*>(lds);
    const float4* const l4r = reinterpret_cast<const float4*>(lds);

    // Phase 1: coalesced float4 global -> LDS via ds_write_b128 (padded).
#pragma unroll
    for (int base = 0; base < LOADN; base += BLOCK * 4) {
        int off = base + tid * 4;
        if (off < LOADN) {
            long t = tStart + off;
            float4 v;
            if (t + 3 < (long)n) {
                v = *reinterpret_cast<const float4*>(sig + t);
            } else {
                v.x = (t + 0 < (long)n) ? sig[t + 0] : 0.f;
                v.y = (t + 1 < (long)n) ? sig[t + 1] : 0.f;
                v.z = (t + 2 < (long)n) ? sig[t + 2] : 0.f;
                v.w = (t + 3 < (long)n) ? sig[t + 3] : 0.f;
            }
            l4w[PAD4(off) >> 2] = v;
        }
    }
    __syncthreads();

    // Phase 2: fused scan + convert, 22 x ds_read_b128 per thread.
    // Thread t: LDS floats [16t, 16t+88): 71 warm, 16 outputs, 1 unused.
    const int p0 = tid * CH;
    float acc = 0.f;
    int res[CH];
#pragma unroll
    for (int k = 0; k < 22; ++k) {
        float4 v = l4r[PAD4(p0 + 4 * k) >> 2];
#pragma unroll
        for (int c = 0; c < 4; ++c) {
            const int e = 4 * k + c;              // compile-time
            float x = (c == 0) ? v.x : (c == 1) ? v.y : (c == 2) ? v.z : v.w;
            if (e < WARM) {
                acc = fmaf(acc, COEF, x);
            } else if (e < WARM + CH) {
                acc = fmaf(acc, COEF, x);
                float s = acc * 32768.f;
                s = fminf(fmaxf(s, -32768.f), 32767.f);
                res[e - WARM] = (int)s;           // trunc toward zero
            }
        }
    }

    // Tail: outputs >= n-SKIP are zero-padded.
    const long oBase = tileBase + p0;
    const long oLim  = (long)n - SKIP;
#pragma unroll
    for (int j = 0; j < CH; ++j)
        if (oBase + j >= oLim) res[j] = 0;

    // Phase 3: direct int4 stores (lane stride 64B; 4 instrs fill full lines).
    if (oBase + CH <= (long)n) {
        int4* o4 = reinterpret_cast<int4*>(out + oBase);
#pragma unroll
        for (int k = 0; k < 4; ++k)
            o4[k] = make_int4(res[4 * k], res[4 * k + 1],
                              res[4 * k + 2], res[4 * k + 3]);
    } else {
#pragma unroll
        for (int j = 0; j < CH; ++j)
            if (oBase + j < (long)n) out[oBase + j] = res[j];
    }
}

extern "C" void kernel_launch(void* const* d_in, const int* in_sizes, int n_in,
                              void* d_out, int out_size, void* d_ws, size_t ws_size,
                              hipStream_t stream) {
    const float* sig = (const float*)d_in[0];
    int* out = (int*)d_out;
    int n = in_sizes[0];
    int grid = (int)(((long)n + TILE - 1) / TILE);
    preemph_kernel<<<grid, BLOCK, 0, stream>>>(sig, out, n);
}

// Round 5
// 231.503 us; speedup vs baseline: 1.0738x; 1.0738x over previous
//
#include <hip/hip_runtime.h>

// Pre-emphasis IIR: out[t] = y[t] + 0.85*out[t-1], shift SKIP=91, scale 32768,
// clip, astype(int16) (trunc toward zero); harness reads d_out as int32.
//
// R4 -> R5: R3's 83us wall was ~40us of LDS-pipe occupancy (scalar ds ops);
// R4 vectorized LDS but regressed on scattered direct stores (64B lane
// stride = 64 partial-line transactions per store instr). R5 = b128 LDS
// everywhere + b128 coalesced store-bounce + nontemporal stores.

#define BLOCK   256
#define CH      16
#define TILE    (BLOCK * CH)        // 4096
#define SKIP    91
#define WARM    71                  // tStart = tileBase + 20 (16B-aligned)
#define COEF    0.85f
#define LOADN   (TILE + 72)         // 4168 floats staged
#define PAD4(p) ((p) + 4 * ((p) >> 5))   // 4-aligned p stays 16B-aligned
#define LDS_F   4688                // > PAD4(4167) = 4687; 18.75 KB -> 8 blk/CU

typedef int v4i __attribute__((ext_vector_type(4)));

__global__ __launch_bounds__(BLOCK) void preemph_kernel(
        const float* __restrict__ sig, int* __restrict__ out, int n) {
    __shared__ float lds[LDS_F];
    const int  tid      = threadIdx.x;
    const long tileBase = (long)blockIdx.x * TILE;
    const long tStart   = tileBase + (SKIP - WARM);   // tileBase + 20, 16B-aligned

    float4* const l4 = reinterpret_cast<float4*>(lds);

    // Phase 1: coalesced float4 global -> ds_write_b128 (padded).
    for (int base = 0; base < LOADN; base += BLOCK * 4) {
        int off = base + tid * 4;
        if (off < LOADN) {
            long t = tStart + off;
            float4 v;
            if (t + 3 < (long)n) {
                v = *reinterpret_cast<const float4*>(sig + t);
            } else {
                v.x = (t + 0 < (long)n) ? sig[t + 0] : 0.f;
                v.y = (t + 1 < (long)n) ? sig[t + 1] : 0.f;
                v.z = (t + 2 < (long)n) ? sig[t + 2] : 0.f;
                v.w = (t + 3 < (long)n) ? sig[t + 3] : 0.f;
            }
            l4[PAD4(off) >> 2] = v;
        }
    }
    __syncthreads();

    // Phase 2: fused scan + convert, 22 x ds_read_b128 per thread.
    // Thread t owns LDS floats [16t, 16t+88): 71 warm-up, 16 outputs, 1 spare.
    const int p0 = tid * CH;
    float acc = 0.f;
    int res[CH];
#pragma unroll
    for (int k = 0; k < 22; ++k) {
        float4 v = l4[PAD4(p0 + 4 * k) >> 2];
#pragma unroll
        for (int c = 0; c < 4; ++c) {
            const int e = 4 * k + c;              // compile-time
            float x = (c == 0) ? v.x : (c == 1) ? v.y : (c == 2) ? v.z : v.w;
            if (e < WARM) {
                acc = fmaf(acc, COEF, x);
            } else if (e < WARM + CH) {
                acc = fmaf(acc, COEF, x);
                float s = acc * 32768.f;
                s = fminf(fmaxf(s, -32768.f), 32767.f);
                res[e - WARM] = (int)s;           // trunc toward zero
            }
        }
    }
    // Tail: outputs >= n-SKIP are zero-padded.
    const long oBase = tileBase + p0;
    const long oLim  = (long)n - SKIP;
#pragma unroll
    for (int j = 0; j < CH; ++j)
        if (oBase + j >= oLim) res[j] = 0;
    __syncthreads();   // phase-2 reads (incl. neighbors' warm-up) must finish

    // Phase 3: int results -> LDS via 4 x ds_write_b128 (bit-cast, same layout).
#pragma unroll
    for (int k = 0; k < 4; ++k) {
        float4 v;
        v.x = __int_as_float(res[4 * k + 0]);
        v.y = __int_as_float(res[4 * k + 1]);
        v.z = __int_as_float(res[4 * k + 2]);
        v.w = __int_as_float(res[4 * k + 3]);
        l4[PAD4(p0 + 4 * k) >> 2] = v;
    }
    __syncthreads();

    // Phase 4: linear ds_read_b128 -> coalesced nontemporal int4 store.
    for (int base = 0; base < TILE; base += BLOCK * 4) {
        int off = base + tid * 4;                 // TILE = 4*1024: no predicate
        long o  = tileBase + off;
        float4 v = l4[PAD4(off) >> 2];
        v4i iv;
        iv.x = __float_as_int(v.x);
        iv.y = __float_as_int(v.y);
        iv.z = __float_as_int(v.z);
        iv.w = __float_as_int(v.w);
        if (o + 3 < (long)n) {
            __builtin_nontemporal_store(iv, reinterpret_cast<v4i*>(out + o));
        } else {
            if (o + 0 < (long)n) out[o + 0] = iv.x;
            if (o + 1 < (long)n) out[o + 1] = iv.y;
            if (o + 2 < (long)n) out[o + 2] = iv.z;
        }
    }
}

extern "C" void kernel_launch(void* const* d_in, const int* in_sizes, int n_in,
                              void* d_out, int out_size, void* d_ws, size_t ws_size,
                              hipStream_t stream) {
    const float* sig = (const float*)d_in[0];
    int* out = (int*)d_out;
    int n = in_sizes[0];
    int grid = (int)(((long)n + TILE - 1) / TILE);
    preemph_kernel<<<grid, BLOCK, 0, stream>>>(sig, out, n);
}